// Round 2
// baseline (643.171 us; speedup 1.0000x reference)
//
#include <hip/hip_runtime.h>
#include <hip/hip_bf16.h>

// ---------- types ----------
typedef short  bf16x8s __attribute__((ext_vector_type(8)));  // 8 bf16 (4 VGPRs)
typedef float  f32x4   __attribute__((ext_vector_type(4)));  // 4 fp32 acc

#define BATCH 32
#define SEQL  2048
#define NROWS (BATCH * SEQL)   // 65536
#define IN    1024
#define HID   1024

// workspace layout
#define WHB_OFF   0u          // 2 MB   bf16 W_h
#define BIAS_OFF  0x200000u   // 4 KB
#define SPART_OFF 0x210000u   // 4 MB   s partials, ROW-MAJOR [65536][16]
#define ABUF_OFF  0x610000u   // 256 KB softmax weights
#define HB_OFF    0x650000u   // 128 MB bf16 h
#define WS_NEED_BF16 ((size_t)HB_OFF + (size_t)NROWS * IN * 2)

// pack two fp32 -> two bf16 (round-up-on-half via +0x8000, v_perm byte select)
__device__ __forceinline__ unsigned int pack2bf(float f0, float f1) {
    unsigned int u0 = __float_as_uint(f0) + 0x8000u;
    unsigned int u1 = __float_as_uint(f1) + 0x8000u;
    return __builtin_amdgcn_perm(u1, u0, 0x07060302u);
}

__device__ __forceinline__ float tanh_fast(float x) {
    float xc = fminf(fmaxf(x, -15.f), 15.f);
    float t  = __builtin_amdgcn_exp2f(xc * 2.8853900817779268f); // e^(2x)
    return (t - 1.f) * __builtin_amdgcn_rcpf(t + 1.f);
}

// async 16B global->LDS (DMA; LDS dest = wave-uniform base + lane*16)
__device__ __forceinline__ void gl2lds16(const void* g, void* l) {
    __builtin_amdgcn_global_load_lds(
        (const __attribute__((address_space(1))) unsigned int*)g,
        (__attribute__((address_space(3))) unsigned int*)l, 16, 0, 0);
}

// XCD-locality swizzle: the 8 cb-siblings of a row-block share bi%8 -> same XCD
// (round-robin) -> A row-block L2-resident across re-reads. [R2: FETCH 1.06GB->92MB]
__device__ __forceinline__ void block_map(int bi, int& rb, int& cb) {
    int xcd  = bi & 7;
    int slot = bi >> 3;
    rb = xcd + 8 * (slot >> 3);
    cb = slot & 7;
}

// ---------- kernel 1: fused [W_h->bf16 + bias] (blocks 0..1023) and h->bf16 (rest) ----
__global__ __launch_bounds__(256) void prep_kernel(const float* __restrict__ ln_w,
                                                   const float* __restrict__ ln_b,
                                                   const float* __restrict__ vq,
                                                   const float* __restrict__ h,
                                                   unsigned short* __restrict__ whb,
                                                   float* __restrict__ bias,
                                                   unsigned short* __restrict__ hb) {
    const int bi = blockIdx.x;
    const int t  = threadIdx.x;
    if (bi < 1024) {
        const int n = bi;
        const int wave = t >> 6;
        const int lane = t & 63;
        float4 v = ((const float4*)(ln_w + (size_t)n * 2048))[t];
        uint2 pk;
        pk.x = pack2bf(v.x, v.y);
        pk.y = pack2bf(v.z, v.w);
        *(uint2*)(whb + (size_t)n * 1024 + t * 4) = pk;
        const float* wrow = ln_w + (size_t)n * 2048 + 1024;
        float s = 0.f;
        #pragma unroll
        for (int j = 0; j < 4; ++j) {
            int k = t + j * 256;
            s += wrow[k] * vq[k];
        }
        #pragma unroll
        for (int off = 32; off; off >>= 1) s += __shfl_xor(s, off);
        __shared__ float red[4];
        if (lane == 0) red[wave] = s;
        __syncthreads();
        if (t == 0) bias[n] = ln_b[n] + red[0] + red[1] + red[2] + red[3];
    } else {
        size_t idx = ((size_t)(bi - 1024) * 256 + t) * 8;
        float4 a = *(const float4*)(h + idx);
        float4 b = *(const float4*)(h + idx + 4);
        uint4 p;
        p.x = pack2bf(a.x, a.y); p.y = pack2bf(a.z, a.w);
        p.z = pack2bf(b.x, b.y); p.w = pack2bf(b.z, b.w);
        *(uint4*)(hb + idx) = p;
    }
}

// ---------- kernel 2: bf16 GEMM, BM=256 x BN=128, BK=32, 8 waves, 2-PHASE PIPELINE --
// Double-buffered LDS; next tile's global_load_lds issued BEFORE current tile's
// ds_read+MFMA; single __syncthreads per K-step (drains vmcnt+lgkm). DMA flight
// overlaps compute instead of serializing (R0 was stage->drain->compute).
// epilogue: s_part[row][16] (row-major) = partial of sum_cols tanh(pre+bias)*v_w
__global__ __launch_bounds__(512) void gemm256_kernel(const unsigned short* __restrict__ hb,
                                                      const unsigned short* __restrict__ whb,
                                                      const float* __restrict__ bias,
                                                      const float* __restrict__ vw,
                                                      float* __restrict__ s_part) {
    __shared__ __align__(16) unsigned short As[2][8192]; // 2 x 16 KB: 256 rows x 32 shorts
    __shared__ __align__(16) unsigned short Bs[2][4096]; // 2 x  8 KB: 128 rows x 32 shorts

    const int tid = threadIdx.x;
    int rb, cb;
    block_map(blockIdx.x, rb, cb);
    const int wave = tid >> 6;
    const int lane = tid & 63;
    const int quad = lane >> 4;
    const int l15  = lane & 15;
    const int wy   = wave >> 1;          // 0..3 row band
    const int wx   = wave & 1;           // 0..1 col band
    const int row0 = rb * 256;
    const int col0 = cb * 128;

    // DMA staging (proven layout: row stride 32 shorts; slot sg holds k-group
    // sg^swz(row), swz=(row>>1)&3; LDS dest lane-linear tid*16B).
    // 512 threads: A issue0 rows 0..127, issue1 rows 128..255; B one issue rows 0..127.
    const int srow = tid >> 2;           // 0..127
    const int sg   = tid & 3;
    const int swz  = (srow >> 1) & 3;
    const unsigned short* gA0 = hb  + (size_t)(row0 + srow) * 1024 + ((sg ^ swz) * 8);
    const unsigned short* gA1 = gA0 + (size_t)128 * 1024;
    const unsigned short* gB0 = whb + (size_t)(col0 + srow) * 1024 + ((sg ^ swz) * 8);
    const int dA0 = tid * 8;             // shorts; bytes [0, 8192)
    const int dA1 = 4096 + tid * 8;      // shorts; bytes [8192, 16384)
    const int dB0 = tid * 8;

    // fragment read pointers (k-invariant; slot = quad ^ ((row>>1)&3))
    const unsigned short* rA[4];
    const unsigned short* rB[4];
    #pragma unroll
    for (int i = 0; i < 4; ++i) {
        int ra = wy * 64 + i * 16 + l15;         // 0..255
        rA[i] = &As[0][0] + ra * 32 + ((quad ^ ((ra >> 1) & 3)) * 8);
        int rn = wx * 64 + i * 16 + l15;         // 0..127
        rB[i] = &Bs[0][0] + rn * 32 + ((quad ^ ((rn >> 1) & 3)) * 8);
    }

    f32x4 acc[4][4];
    #pragma unroll
    for (int i = 0; i < 4; ++i)
        #pragma unroll
        for (int j = 0; j < 4; ++j)
            acc[i][j] = (f32x4){0.f, 0.f, 0.f, 0.f};

    // prologue: stage tile 0 into buffer 0
    gl2lds16(gA0, &As[0][dA0]);
    gl2lds16(gA1, &As[0][dA1]);
    gl2lds16(gB0, &Bs[0][dB0]);
    __syncthreads();                     // vmcnt(0) drained by barrier

    int cur = 0;
    for (int k0 = 0; k0 < 1024; k0 += 32) {
        // issue next tile's DMA into the other buffer (flight hides under compute)
        if (k0 + 32 < 1024) {
            const int nxt = cur ^ 1;
            gl2lds16(gA0 + k0 + 32, &As[nxt][dA0]);
            gl2lds16(gA1 + k0 + 32, &As[nxt][dA1]);
            gl2lds16(gB0 + k0 + 32, &Bs[nxt][dB0]);
        }

        const int aoff = cur * 8192;     // shorts
        const int boff = cur * 4096;
        bf16x8s af[4], bfv[4];
        #pragma unroll
        for (int i = 0; i < 4; ++i) af[i]  = *(const bf16x8s*)(rA[i] + aoff);
        #pragma unroll
        for (int i = 0; i < 4; ++i) bfv[i] = *(const bf16x8s*)(rB[i] + boff);
        #pragma unroll
        for (int mt = 0; mt < 4; ++mt)
            #pragma unroll
            for (int nt = 0; nt < 4; ++nt)
                acc[mt][nt] = __builtin_amdgcn_mfma_f32_16x16x32_bf16(af[mt], bfv[nt], acc[mt][nt], 0, 0, 0);

        __syncthreads();                 // reads of buf[cur] done; DMA to buf[nxt] drained
        cur ^= 1;
    }

    // epilogue: C/D layout col=lane&15, row=quad*4+r [m89/m91]
    const int colb = col0 + wx * 64 + l15;
    float vwv[4], bv[4];
    #pragma unroll
    for (int nt = 0; nt < 4; ++nt) {
        vwv[nt] = vw[colb + nt * 16];
        bv[nt]  = bias[colb + nt * 16];
    }
    const int rowb = row0 + wy * 64 + quad * 4;
    const int colp = cb * 2 + wx;        // partial slot 0..15
    #pragma unroll
    for (int mt = 0; mt < 4; ++mt) {
        #pragma unroll
        for (int r = 0; r < 4; ++r) {
            float p = 0.f;
            #pragma unroll
            for (int nt = 0; nt < 4; ++nt)
                p += tanh_fast(acc[mt][nt][r] + bv[nt]) * vwv[nt];
            p += __shfl_xor(p, 1);
            p += __shfl_xor(p, 2);
            p += __shfl_xor(p, 4);
            p += __shfl_xor(p, 8);
            if (l15 == 0) s_part[(size_t)(rowb + mt * 16 + r) * 16 + colp] = p;
        }
    }
}

// ---------- kernel 2b: fp32-A fallback (inline pack), only if ws too small ----------
__global__ __launch_bounds__(256) void gemm_f32_kernel(const float* __restrict__ hmat,
                                                       const unsigned short* __restrict__ whb,
                                                       const float* __restrict__ bias,
                                                       const float* __restrict__ vw,
                                                       float* __restrict__ s_part) {
    __shared__ __align__(16) unsigned short As[4096];
    __shared__ __align__(16) unsigned short Bs[4096];
    const int tid = threadIdx.x;
    int rb, cb;
    block_map(blockIdx.x, rb, cb);
    const int wave = tid >> 6;
    const int lane = tid & 63;
    const int quad = lane >> 4;
    const int l15  = lane & 15;
    const int wy   = wave >> 1;
    const int wx   = wave & 1;
    const int row0 = rb * 128;
    const int col0 = cb * 128;
    const int srow = tid >> 2;
    const int sg   = tid & 3;
    const int swz  = (srow >> 1) & 3;
    const float*          gA0 = hmat + (size_t)(row0 + srow)      * 1024 + sg * 8;
    const float*          gA1 = hmat + (size_t)(row0 + srow + 64) * 1024 + sg * 8;
    const unsigned short* gB0 = whb  + (size_t)(col0 + srow)      * 1024 + ((sg ^ swz) * 8);
    unsigned short* wA0 = As + srow * 32 + ((sg ^ swz) * 8);
    unsigned short* wA1 = wA0 + 64 * 32;
    unsigned short* lB0 = Bs + tid * 8;
    const unsigned short* rA[4];
    const unsigned short* rB[4];
    #pragma unroll
    for (int i = 0; i < 4; ++i) {
        int ra = wy * 64 + i * 16 + l15;
        rA[i] = As + ra * 32 + ((quad ^ ((ra >> 1) & 3)) * 8);
        int rn = wx * 64 + i * 16 + l15;
        rB[i] = Bs + rn * 32 + ((quad ^ ((rn >> 1) & 3)) * 8);
    }
    f32x4 acc[4][4];
    #pragma unroll
    for (int i = 0; i < 4; ++i)
        #pragma unroll
        for (int j = 0; j < 4; ++j)
            acc[i][j] = (f32x4){0.f, 0.f, 0.f, 0.f};
    for (int k0 = 0; k0 < 1024; k0 += 32) {
        float4 va0 = *(const float4*)(gA0 + k0);
        float4 va1 = *(const float4*)(gA0 + k0 + 4);
        float4 va2 = *(const float4*)(gA1 + k0);
        float4 va3 = *(const float4*)(gA1 + k0 + 4);
        __syncthreads();
        gl2lds16(gB0 + k0, lB0);
        gl2lds16(gB0 + 65536 + k0, lB0 + 2048);
        uint4 pa0, pa1;
        pa0.x = pack2bf(va0.x, va0.y); pa0.y = pack2bf(va0.z, va0.w);
        pa0.z = pack2bf(va1.x, va1.y); pa0.w = pack2bf(va1.z, va1.w);
        pa1.x = pack2bf(va2.x, va2.y); pa1.y = pack2bf(va2.z, va2.w);
        pa1.z = pack2bf(va3.x, va3.y); pa1.w = pack2bf(va3.z, va3.w);
        *(uint4*)wA0 = pa0;
        *(uint4*)wA1 = pa1;
        __syncthreads();
        bf16x8s af[4], bfv[4];
        #pragma unroll
        for (int i = 0; i < 4; ++i) af[i]  = *(const bf16x8s*)rA[i];
        #pragma unroll
        for (int i = 0; i < 4; ++i) bfv[i] = *(const bf16x8s*)rB[i];
        #pragma unroll
        for (int mt = 0; mt < 4; ++mt)
            #pragma unroll
            for (int nt = 0; nt < 4; ++nt)
                acc[mt][nt] = __builtin_amdgcn_mfma_f32_16x16x32_bf16(af[mt], bfv[nt], acc[mt][nt], 0, 0, 0);
    }
    const int colb = col0 + wx * 64 + l15;
    float vwv[4], bv[4];
    #pragma unroll
    for (int nt = 0; nt < 4; ++nt) {
        vwv[nt] = vw[colb + nt * 16];
        bv[nt]  = bias[colb + nt * 16];
    }
    const int rowb = row0 + wy * 64 + quad * 4;
    const int colp = cb * 2 + wx;
    #pragma unroll
    for (int mt = 0; mt < 4; ++mt) {
        #pragma unroll
        for (int r = 0; r < 4; ++r) {
            float p = 0.f;
            #pragma unroll
            for (int nt = 0; nt < 4; ++nt)
                p += tanh_fast(acc[mt][nt][r] + bv[nt]) * vwv[nt];
            p += __shfl_xor(p, 1);
            p += __shfl_xor(p, 2);
            p += __shfl_xor(p, 4);
            p += __shfl_xor(p, 8);
            if (l15 == 0) s_part[(size_t)(rowb + mt * 16 + r) * 16 + colp] = p;
        }
    }
}

// ---------- kernel 3: sum partials + masked softmax; also zeroes d_out ----------
// s_part is row-major [65536][16]: 64B/row, read as 4 contiguous float4 per l.
__global__ __launch_bounds__(512) void softmax_kernel(const float* __restrict__ s_part,
                                                      const int* __restrict__ mask,
                                                      float* __restrict__ a_buf,
                                                      float* __restrict__ out) {
    const int b    = blockIdx.x;
    const int t    = threadIdx.x;
    const int wave = t >> 6;
    const int lane = t & 63;
    // zero the output slice this batch will atomically accumulate into (kernel 4)
    ((float2*)(out + b * 1024))[t] = (float2){0.f, 0.f};
    __shared__ float redm[8];
    __shared__ float reds[8];
    float sv[4];
    float mx = -3.0e38f;
    #pragma unroll
    for (int j = 0; j < 4; ++j) {
        int l = t + j * 512;
        const float4* pr = (const float4*)(s_part + ((size_t)b * 2048 + l) * 16);
        float4 q0 = pr[0], q1 = pr[1], q2 = pr[2], q3 = pr[3];
        float v = (q0.x + q0.y + q0.z + q0.w) + (q1.x + q1.y + q1.z + q1.w)
                + (q2.x + q2.y + q2.z + q2.w) + (q3.x + q3.y + q3.z + q3.w);
        if (mask[b * 2048 + l] == 0) v -= 10000.f;
        sv[j] = v;
        mx = fmaxf(mx, v);
    }
    #pragma unroll
    for (int off = 32; off; off >>= 1) mx = fmaxf(mx, __shfl_xor(mx, off));
    if (lane == 0) redm[wave] = mx;
    __syncthreads();
    mx = redm[0];
    #pragma unroll
    for (int w = 1; w < 8; ++w) mx = fmaxf(mx, redm[w]);
    float sum = 0.f;
    #pragma unroll
    for (int j = 0; j < 4; ++j) {
        sv[j] = __expf(sv[j] - mx);
        sum += sv[j];
    }
    #pragma unroll
    for (int off = 32; off; off >>= 1) sum += __shfl_xor(sum, off);
    if (lane == 0) reds[wave] = sum;
    __syncthreads();
    sum = reds[0];
    #pragma unroll
    for (int w = 1; w < 8; ++w) sum += reds[w];
    float inv = 1.f / sum;
    #pragma unroll
    for (int j = 0; j < 4; ++j)
        a_buf[b * 2048 + t + j * 512] = sv[j] * inv;
}

// ---------- kernel 4a: r[b,i] = sum_l a[b,l]*h[b,l,i], bf16 h (halved read) ----------
__global__ __launch_bounds__(256) void r_bf16_kernel(const unsigned short* __restrict__ hb,
                                                     const float* __restrict__ a_buf,
                                                     float* __restrict__ out) {
    const int b  = blockIdx.x >> 5;
    const int lc = blockIdx.x & 31;
    const int t  = threadIdx.x;
    __shared__ float aw[64];
    if (t < 64) aw[t] = a_buf[b * 2048 + lc * 64 + t];
    __syncthreads();
    const uint2* hp = (const uint2*)(hb + (size_t)(b * 2048 + lc * 64) * 1024) + t;
    float a0 = 0.f, a1 = 0.f, a2 = 0.f, a3 = 0.f;
    #pragma unroll 8
    for (int l = 0; l < 64; ++l) {
        uint2 v = hp[(size_t)l * 256];
        float av = aw[l];
        a0 += av * __uint_as_float(v.x << 16);
        a1 += av * __uint_as_float(v.x & 0xffff0000u);
        a2 += av * __uint_as_float(v.y << 16);
        a3 += av * __uint_as_float(v.y & 0xffff0000u);
    }
    float* op = out + b * 1024 + t * 4;
    atomicAdd(op + 0, a0);
    atomicAdd(op + 1, a1);
    atomicAdd(op + 2, a2);
    atomicAdd(op + 3, a3);
}

// ---------- kernel 4b: fp32 fallback ----------
__global__ __launch_bounds__(256) void r_f32_kernel(const float* __restrict__ hmat,
                                                    const float* __restrict__ a_buf,
                                                    float* __restrict__ out) {
    const int b  = blockIdx.x >> 5;
    const int lc = blockIdx.x & 31;
    const int t  = threadIdx.x;
    __shared__ float aw[64];
    if (t < 64) aw[t] = a_buf[b * 2048 + lc * 64 + t];
    __syncthreads();
    const float4* hp = (const float4*)hmat + (size_t)(b * 2048 + lc * 64) * 256;
    float ax = 0.f, ay = 0.f, az = 0.f, aq = 0.f;
    #pragma unroll 8
    for (int l = 0; l < 64; ++l) {
        float4 hv = hp[(size_t)l * 256 + t];
        float av = aw[l];
        ax += av * hv.x; ay += av * hv.y; az += av * hv.z; aq += av * hv.w;
    }
    float* op = out + b * 1024 + t * 4;
    atomicAdd(op + 0, ax);
    atomicAdd(op + 1, ay);
    atomicAdd(op + 2, az);
    atomicAdd(op + 3, aq);
}

// ---------- launch (4 dispatches, no memsets) ----------
extern "C" void kernel_launch(void* const* d_in, const int* in_sizes, int n_in,
                              void* d_out, int out_size, void* d_ws, size_t ws_size,
                              hipStream_t stream) {
    const float* h    = (const float*)d_in[0];
    const int*   mask = (const int*)d_in[1];
    const float* ln_w = (const float*)d_in[2];
    const float* ln_b = (const float*)d_in[3];
    const float* v_w  = (const float*)d_in[4];
    const float* vq   = (const float*)d_in[5];
    float* out = (float*)d_out;

    char* ws = (char*)d_ws;
    unsigned short* whb = (unsigned short*)(ws + WHB_OFF);
    float* bias         = (float*)(ws + BIAS_OFF);
    float* s_part       = (float*)(ws + SPART_OFF);
    float* a_buf        = (float*)(ws + ABUF_OFF);
    unsigned short* hb  = (unsigned short*)(ws + HB_OFF);

    const bool use_bf16_h = (ws_size >= WS_NEED_BF16);

    if (use_bf16_h) {
        prep_kernel<<<1024 + 32768, 256, 0, stream>>>(ln_w, ln_b, vq, h, whb, bias, hb);
        gemm256_kernel<<<(NROWS / 256) * (HID / 128), 512, 0, stream>>>(hb, whb, bias, v_w, s_part);
        softmax_kernel<<<BATCH, 512, 0, stream>>>(s_part, mask, a_buf, out);
        r_bf16_kernel<<<BATCH * 32, 256, 0, stream>>>(hb, a_buf, out);
    } else {
        prep_kernel<<<1024, 256, 0, stream>>>(ln_w, ln_b, vq, h, whb, bias, hb);
        gemm_f32_kernel<<<(NROWS / 128) * (HID / 128), 256, 0, stream>>>(h, whb, bias, v_w, s_part);
        softmax_kernel<<<BATCH, 512, 0, stream>>>(s_part, mask, a_buf, out);
        r_f32_kernel<<<BATCH * 32, 256, 0, stream>>>(h, a_buf, out);
    }
}

// Round 4
// 554.416 us; speedup vs baseline: 1.1601x; 1.1601x over previous
//
#include <hip/hip_runtime.h>
#include <hip/hip_bf16.h>

// ---------- types ----------
typedef short  bf16x8s __attribute__((ext_vector_type(8)));  // 8 bf16 (4 VGPRs)
typedef float  f32x4   __attribute__((ext_vector_type(4)));  // 4 fp32 acc

#define BATCH 32
#define SEQL  2048
#define NROWS (BATCH * SEQL)   // 65536
#define IN    1024
#define HID   1024

// workspace layout
#define WHB_OFF   0u          // 2 MB   bf16 W_h
#define BIAS_OFF  0x200000u   // 4 KB
#define SPART_OFF 0x210000u   // 4 MB   s partials, ROW-MAJOR [65536][16]
#define ABUF_OFF  0x610000u   // 256 KB softmax weights
#define HB_OFF    0x650000u   // 128 MB bf16 h
// r partials reuse the s_part region (dead after softmax; stream order serializes)
#define RPART_OFF SPART_OFF   // 4 MB: [32 chunks][32 batch][1024]
#define WS_NEED_BF16 ((size_t)HB_OFF + (size_t)NROWS * IN * 2)

// pack two fp32 -> two bf16 (round-up-on-half via +0x8000, v_perm byte select)
__device__ __forceinline__ unsigned int pack2bf(float f0, float f1) {
    unsigned int u0 = __float_as_uint(f0) + 0x8000u;
    unsigned int u1 = __float_as_uint(f1) + 0x8000u;
    return __builtin_amdgcn_perm(u1, u0, 0x07060302u);
}

__device__ __forceinline__ float tanh_fast(float x) {
    float xc = fminf(fmaxf(x, -15.f), 15.f);
    float t  = __builtin_amdgcn_exp2f(xc * 2.8853900817779268f); // e^(2x)
    return (t - 1.f) * __builtin_amdgcn_rcpf(t + 1.f);
}

// async 16B global->LDS (DMA; LDS dest = wave-uniform base + lane*16)
__device__ __forceinline__ void gl2lds16(const void* g, void* l) {
    __builtin_amdgcn_global_load_lds(
        (const __attribute__((address_space(1))) unsigned int*)g,
        (__attribute__((address_space(3))) unsigned int*)l, 16, 0, 0);
}

// XCD-locality swizzle: the 8 cb-siblings of a row-block share bi%8 -> same XCD
// (round-robin) -> A row-block L2-resident across re-reads. [R2: FETCH 1.06GB->92MB]
__device__ __forceinline__ void block_map(int bi, int& rb, int& cb) {
    int xcd  = bi & 7;
    int slot = bi >> 3;
    rb = xcd + 8 * (slot >> 3);
    cb = slot & 7;
}

// ---------- kernel 1: fused [W_h->bf16 + bias] (blocks 0..1023) and h->bf16 (rest) ----
__global__ __launch_bounds__(256) void prep_kernel(const float* __restrict__ ln_w,
                                                   const float* __restrict__ ln_b,
                                                   const float* __restrict__ vq,
                                                   const float* __restrict__ h,
                                                   unsigned short* __restrict__ whb,
                                                   float* __restrict__ bias,
                                                   unsigned short* __restrict__ hb) {
    const int bi = blockIdx.x;
    const int t  = threadIdx.x;
    if (bi < 1024) {
        const int n = bi;
        const int wave = t >> 6;
        const int lane = t & 63;
        float4 v = ((const float4*)(ln_w + (size_t)n * 2048))[t];
        uint2 pk;
        pk.x = pack2bf(v.x, v.y);
        pk.y = pack2bf(v.z, v.w);
        *(uint2*)(whb + (size_t)n * 1024 + t * 4) = pk;
        const float* wrow = ln_w + (size_t)n * 2048 + 1024;
        float s = 0.f;
        #pragma unroll
        for (int j = 0; j < 4; ++j) {
            int k = t + j * 256;
            s += wrow[k] * vq[k];
        }
        #pragma unroll
        for (int off = 32; off; off >>= 1) s += __shfl_xor(s, off);
        __shared__ float red[4];
        if (lane == 0) red[wave] = s;
        __syncthreads();
        if (t == 0) bias[n] = ln_b[n] + red[0] + red[1] + red[2] + red[3];
    } else {
        size_t idx = ((size_t)(bi - 1024) * 256 + t) * 8;
        float4 a = *(const float4*)(h + idx);
        float4 b = *(const float4*)(h + idx + 4);
        uint4 p;
        p.x = pack2bf(a.x, a.y); p.y = pack2bf(a.z, a.w);
        p.z = pack2bf(b.x, b.y); p.w = pack2bf(b.z, b.w);
        *(uint4*)(hb + idx) = p;
    }
}

// ---------- kernel 2: bf16 GEMM, BM=256 x BN=128, BK=32, 8 waves (R0 structure) ------
// Single-buffer 24KB LDS, stage->barrier->compute per K-step. Occupancy (~4 blk/CU)
// provides the latency hiding; explicit dbuf regressed (R2: occ 43->23%, 172->246us).
// epilogue: s_part[row][16] (row-major) = partial of sum_cols tanh(pre+bias)*v_w
__global__ __launch_bounds__(512) void gemm256_kernel(const unsigned short* __restrict__ hb,
                                                      const unsigned short* __restrict__ whb,
                                                      const float* __restrict__ bias,
                                                      const float* __restrict__ vw,
                                                      float* __restrict__ s_part) {
    __shared__ __align__(16) unsigned short As[8192]; // 16 KB: 256 rows x 32 shorts
    __shared__ __align__(16) unsigned short Bs[4096]; // 8 KB : 128 rows x 32 shorts

    const int tid = threadIdx.x;
    int rb, cb;
    block_map(blockIdx.x, rb, cb);
    const int wave = tid >> 6;
    const int lane = tid & 63;
    const int quad = lane >> 4;
    const int l15  = lane & 15;
    const int wy   = wave >> 1;          // 0..3 row band
    const int wx   = wave & 1;           // 0..1 col band
    const int row0 = rb * 256;
    const int col0 = cb * 128;

    // DMA staging (proven layout: row stride 32 shorts; slot sg holds k-group
    // sg^swz(row), swz=(row>>1)&3; LDS dest lane-linear tid*16B).
    // 512 threads: A issue0 rows 0..127, issue1 rows 128..255; B one issue rows 0..127.
    const int srow = tid >> 2;           // 0..127
    const int sg   = tid & 3;
    const int swz  = (srow >> 1) & 3;
    const unsigned short* gA0 = hb  + (size_t)(row0 + srow) * 1024 + ((sg ^ swz) * 8);
    const unsigned short* gA1 = gA0 + (size_t)128 * 1024;
    const unsigned short* gB0 = whb + (size_t)(col0 + srow) * 1024 + ((sg ^ swz) * 8);
    unsigned short* lA0 = As + tid * 8;          // bytes [0, 8192)
    unsigned short* lA1 = As + 4096 + tid * 8;   // bytes [8192, 16384)
    unsigned short* lB0 = Bs + tid * 8;          // bytes [0, 8192)

    // fragment read pointers (k-invariant; slot = quad ^ ((row>>1)&3))
    const unsigned short* rA[4];
    const unsigned short* rB[4];
    #pragma unroll
    for (int i = 0; i < 4; ++i) {
        int ra = wy * 64 + i * 16 + l15;         // 0..255
        rA[i] = As + ra * 32 + ((quad ^ ((ra >> 1) & 3)) * 8);
        int rn = wx * 64 + i * 16 + l15;         // 0..127
        rB[i] = Bs + rn * 32 + ((quad ^ ((rn >> 1) & 3)) * 8);
    }

    f32x4 acc[4][4];
    #pragma unroll
    for (int i = 0; i < 4; ++i)
        #pragma unroll
        for (int j = 0; j < 4; ++j)
            acc[i][j] = (f32x4){0.f, 0.f, 0.f, 0.f};

    for (int k0 = 0; k0 < 1024; k0 += 32) {
        __syncthreads();                 // prev iter's frag reads complete
        gl2lds16(gA0 + k0, lA0);
        gl2lds16(gA1 + k0, lA1);
        gl2lds16(gB0 + k0, lB0);
        __syncthreads();                 // DMA drained (barrier waits vmcnt(0))

        bf16x8s af[4], bfv[4];
        #pragma unroll
        for (int i = 0; i < 4; ++i) af[i]  = *(const bf16x8s*)rA[i];
        #pragma unroll
        for (int i = 0; i < 4; ++i) bfv[i] = *(const bf16x8s*)rB[i];
        #pragma unroll
        for (int mt = 0; mt < 4; ++mt)
            #pragma unroll
            for (int nt = 0; nt < 4; ++nt)
                acc[mt][nt] = __builtin_amdgcn_mfma_f32_16x16x32_bf16(af[mt], bfv[nt], acc[mt][nt], 0, 0, 0);
    }

    // epilogue: C/D layout col=lane&15, row=quad*4+r [m89/m91]
    const int colb = col0 + wx * 64 + l15;
    float vwv[4], bv[4];
    #pragma unroll
    for (int nt = 0; nt < 4; ++nt) {
        vwv[nt] = vw[colb + nt * 16];
        bv[nt]  = bias[colb + nt * 16];
    }
    const int rowb = row0 + wy * 64 + quad * 4;
    const int colp = cb * 2 + wx;        // partial slot 0..15
    #pragma unroll
    for (int mt = 0; mt < 4; ++mt) {
        #pragma unroll
        for (int r = 0; r < 4; ++r) {
            float p = 0.f;
            #pragma unroll
            for (int nt = 0; nt < 4; ++nt)
                p += tanh_fast(acc[mt][nt][r] + bv[nt]) * vwv[nt];
            p += __shfl_xor(p, 1);
            p += __shfl_xor(p, 2);
            p += __shfl_xor(p, 4);
            p += __shfl_xor(p, 8);
            if (l15 == 0) s_part[(size_t)(rowb + mt * 16 + r) * 16 + colp] = p;
        }
    }
}

// ---------- kernel 2b: fp32-A fallback (inline pack), only if ws too small ----------
__global__ __launch_bounds__(256) void gemm_f32_kernel(const float* __restrict__ hmat,
                                                       const unsigned short* __restrict__ whb,
                                                       const float* __restrict__ bias,
                                                       const float* __restrict__ vw,
                                                       float* __restrict__ s_part) {
    __shared__ __align__(16) unsigned short As[4096];
    __shared__ __align__(16) unsigned short Bs[4096];
    const int tid = threadIdx.x;
    int rb, cb;
    block_map(blockIdx.x, rb, cb);
    const int wave = tid >> 6;
    const int lane = tid & 63;
    const int quad = lane >> 4;
    const int l15  = lane & 15;
    const int wy   = wave >> 1;
    const int wx   = wave & 1;
    const int row0 = rb * 128;
    const int col0 = cb * 128;
    const int srow = tid >> 2;
    const int sg   = tid & 3;
    const int swz  = (srow >> 1) & 3;
    const float*          gA0 = hmat + (size_t)(row0 + srow)      * 1024 + sg * 8;
    const float*          gA1 = hmat + (size_t)(row0 + srow + 64) * 1024 + sg * 8;
    const unsigned short* gB0 = whb  + (size_t)(col0 + srow)      * 1024 + ((sg ^ swz) * 8);
    unsigned short* wA0 = As + srow * 32 + ((sg ^ swz) * 8);
    unsigned short* wA1 = wA0 + 64 * 32;
    unsigned short* lB0 = Bs + tid * 8;
    const unsigned short* rA[4];
    const unsigned short* rB[4];
    #pragma unroll
    for (int i = 0; i < 4; ++i) {
        int ra = wy * 64 + i * 16 + l15;
        rA[i] = As + ra * 32 + ((quad ^ ((ra >> 1) & 3)) * 8);
        int rn = wx * 64 + i * 16 + l15;
        rB[i] = Bs + rn * 32 + ((quad ^ ((rn >> 1) & 3)) * 8);
    }
    f32x4 acc[4][4];
    #pragma unroll
    for (int i = 0; i < 4; ++i)
        #pragma unroll
        for (int j = 0; j < 4; ++j)
            acc[i][j] = (f32x4){0.f, 0.f, 0.f, 0.f};
    for (int k0 = 0; k0 < 1024; k0 += 32) {
        float4 va0 = *(const float4*)(gA0 + k0);
        float4 va1 = *(const float4*)(gA0 + k0 + 4);
        float4 va2 = *(const float4*)(gA1 + k0);
        float4 va3 = *(const float4*)(gA1 + k0 + 4);
        __syncthreads();
        gl2lds16(gB0 + k0, lB0);
        gl2lds16(gB0 + 65536 + k0, lB0 + 2048);
        uint4 pa0, pa1;
        pa0.x = pack2bf(va0.x, va0.y); pa0.y = pack2bf(va0.z, va0.w);
        pa0.z = pack2bf(va1.x, va1.y); pa0.w = pack2bf(va1.z, va1.w);
        pa1.x = pack2bf(va2.x, va2.y); pa1.y = pack2bf(va2.z, va2.w);
        pa1.z = pack2bf(va3.x, va3.y); pa1.w = pack2bf(va3.z, va3.w);
        *(uint4*)wA0 = pa0;
        *(uint4*)wA1 = pa1;
        __syncthreads();
        bf16x8s af[4], bfv[4];
        #pragma unroll
        for (int i = 0; i < 4; ++i) af[i]  = *(const bf16x8s*)rA[i];
        #pragma unroll
        for (int i = 0; i < 4; ++i) bfv[i] = *(const bf16x8s*)rB[i];
        #pragma unroll
        for (int mt = 0; mt < 4; ++mt)
            #pragma unroll
            for (int nt = 0; nt < 4; ++nt)
                acc[mt][nt] = __builtin_amdgcn_mfma_f32_16x16x32_bf16(af[mt], bfv[nt], acc[mt][nt], 0, 0, 0);
    }
    const int colb = col0 + wx * 64 + l15;
    float vwv[4], bv[4];
    #pragma unroll
    for (int nt = 0; nt < 4; ++nt) {
        vwv[nt] = vw[colb + nt * 16];
        bv[nt]  = bias[colb + nt * 16];
    }
    const int rowb = row0 + wy * 64 + quad * 4;
    const int colp = cb * 2 + wx;
    #pragma unroll
    for (int mt = 0; mt < 4; ++mt) {
        #pragma unroll
        for (int r = 0; r < 4; ++r) {
            float p = 0.f;
            #pragma unroll
            for (int nt = 0; nt < 4; ++nt)
                p += tanh_fast(acc[mt][nt][r] + bv[nt]) * vwv[nt];
            p += __shfl_xor(p, 1);
            p += __shfl_xor(p, 2);
            p += __shfl_xor(p, 4);
            p += __shfl_xor(p, 8);
            if (l15 == 0) s_part[(size_t)(rowb + mt * 16 + r) * 16 + colp] = p;
        }
    }
}

// ---------- kernel 3: sum partials + masked softmax (row-major s_part) ----------
__global__ __launch_bounds__(512) void softmax_kernel(const float* __restrict__ s_part,
                                                      const int* __restrict__ mask,
                                                      float* __restrict__ a_buf) {
    const int b    = blockIdx.x;
    const int t    = threadIdx.x;
    const int wave = t >> 6;
    const int lane = t & 63;
    __shared__ float redm[8];
    __shared__ float reds[8];
    float sv[4];
    float mx = -3.0e38f;
    #pragma unroll
    for (int j = 0; j < 4; ++j) {
        int l = t + j * 512;
        const float4* pr = (const float4*)(s_part + ((size_t)b * 2048 + l) * 16);
        float4 q0 = pr[0], q1 = pr[1], q2 = pr[2], q3 = pr[3];
        float v = (q0.x + q0.y + q0.z + q0.w) + (q1.x + q1.y + q1.z + q1.w)
                + (q2.x + q2.y + q2.z + q2.w) + (q3.x + q3.y + q3.z + q3.w);
        if (mask[b * 2048 + l] == 0) v -= 10000.f;
        sv[j] = v;
        mx = fmaxf(mx, v);
    }
    #pragma unroll
    for (int off = 32; off; off >>= 1) mx = fmaxf(mx, __shfl_xor(mx, off));
    if (lane == 0) redm[wave] = mx;
    __syncthreads();
    mx = redm[0];
    #pragma unroll
    for (int w = 1; w < 8; ++w) mx = fmaxf(mx, redm[w]);
    float sum = 0.f;
    #pragma unroll
    for (int j = 0; j < 4; ++j) {
        sv[j] = __expf(sv[j] - mx);
        sum += sv[j];
    }
    #pragma unroll
    for (int off = 32; off; off >>= 1) sum += __shfl_xor(sum, off);
    if (lane == 0) reds[wave] = sum;
    __syncthreads();
    sum = reds[0];
    #pragma unroll
    for (int w = 1; w < 8; ++w) sum += reds[w];
    float inv = 1.f / sum;
    #pragma unroll
    for (int j = 0; j < 4; ++j)
        a_buf[b * 2048 + t + j * 512] = sv[j] * inv;
}

// ---------- kernel 4a: r partials, NO atomics: r_part[lc][b][i] ----------
__global__ __launch_bounds__(256) void r_bf16_part_kernel(const unsigned short* __restrict__ hb,
                                                          const float* __restrict__ a_buf,
                                                          float* __restrict__ r_part) {
    const int b  = blockIdx.x >> 5;
    const int lc = blockIdx.x & 31;
    const int t  = threadIdx.x;
    __shared__ float aw[64];
    if (t < 64) aw[t] = a_buf[b * 2048 + lc * 64 + t];
    __syncthreads();
    const uint2* hp = (const uint2*)(hb + (size_t)(b * 2048 + lc * 64) * 1024) + t;
    float a0 = 0.f, a1 = 0.f, a2 = 0.f, a3 = 0.f;
    #pragma unroll 8
    for (int l = 0; l < 64; ++l) {
        uint2 v = hp[(size_t)l * 256];
        float av = aw[l];
        a0 += av * __uint_as_float(v.x << 16);
        a1 += av * __uint_as_float(v.x & 0xffff0000u);
        a2 += av * __uint_as_float(v.y << 16);
        a3 += av * __uint_as_float(v.y & 0xffff0000u);
    }
    float4 res = {a0, a1, a2, a3};
    *(float4*)(r_part + ((size_t)lc * 32 + b) * 1024 + t * 4) = res;
}

// ---------- kernel 4b: fp32 fallback partials ----------
__global__ __launch_bounds__(256) void r_f32_part_kernel(const float* __restrict__ hmat,
                                                         const float* __restrict__ a_buf,
                                                         float* __restrict__ r_part) {
    const int b  = blockIdx.x >> 5;
    const int lc = blockIdx.x & 31;
    const int t  = threadIdx.x;
    __shared__ float aw[64];
    if (t < 64) aw[t] = a_buf[b * 2048 + lc * 64 + t];
    __syncthreads();
    const float4* hp = (const float4*)hmat + (size_t)(b * 2048 + lc * 64) * 256;
    float ax = 0.f, ay = 0.f, az = 0.f, aq = 0.f;
    #pragma unroll 8
    for (int l = 0; l < 64; ++l) {
        float4 hv = hp[(size_t)l * 256 + t];
        float av = aw[l];
        ax += av * hv.x; ay += av * hv.y; az += av * hv.z; aq += av * hv.w;
    }
    float4 res = {ax, ay, az, aq};
    *(float4*)(r_part + ((size_t)lc * 32 + b) * 1024 + t * 4) = res;
}

// ---------- kernel 5: reduce 32 partials -> out ----------
__global__ __launch_bounds__(256) void r_reduce_kernel(const float* __restrict__ r_part,
                                                       float* __restrict__ out) {
    const int b = blockIdx.x;
    const int t = threadIdx.x;
    float4 s = {0.f, 0.f, 0.f, 0.f};
    #pragma unroll 8
    for (int lc = 0; lc < 32; ++lc) {
        float4 v = *(const float4*)(r_part + ((size_t)lc * 32 + b) * 1024 + t * 4);
        s.x += v.x; s.y += v.y; s.z += v.z; s.w += v.w;
    }
    *(float4*)(out + b * 1024 + t * 4) = s;
}

// ---------- launch (5 dispatches, no memsets, no atomics) ----------
extern "C" void kernel_launch(void* const* d_in, const int* in_sizes, int n_in,
                              void* d_out, int out_size, void* d_ws, size_t ws_size,
                              hipStream_t stream) {
    const float* h    = (const float*)d_in[0];
    const int*   mask = (const int*)d_in[1];
    const float* ln_w = (const float*)d_in[2];
    const float* ln_b = (const float*)d_in[3];
    const float* v_w  = (const float*)d_in[4];
    const float* vq   = (const float*)d_in[5];
    float* out = (float*)d_out;

    char* ws = (char*)d_ws;
    unsigned short* whb = (unsigned short*)(ws + WHB_OFF);
    float* bias         = (float*)(ws + BIAS_OFF);
    float* s_part       = (float*)(ws + SPART_OFF);
    float* a_buf        = (float*)(ws + ABUF_OFF);
    unsigned short* hb  = (unsigned short*)(ws + HB_OFF);
    float* r_part       = (float*)(ws + RPART_OFF);  // aliases s_part (dead after softmax)

    const bool use_bf16_h = (ws_size >= WS_NEED_BF16);

    if (use_bf16_h) {
        prep_kernel<<<1024 + 32768, 256, 0, stream>>>(ln_w, ln_b, vq, h, whb, bias, hb);
        gemm256_kernel<<<(NROWS / 256) * (HID / 128), 512, 0, stream>>>(hb, whb, bias, v_w, s_part);
        softmax_kernel<<<BATCH, 512, 0, stream>>>(s_part, mask, a_buf);
        r_bf16_part_kernel<<<BATCH * 32, 256, 0, stream>>>(hb, a_buf, r_part);
        r_reduce_kernel<<<BATCH, 256, 0, stream>>>(r_part, out);
    } else {
        prep_kernel<<<1024, 256, 0, stream>>>(ln_w, ln_b, vq, h, whb, bias, hb);
        gemm_f32_kernel<<<(NROWS / 128) * (HID / 128), 256, 0, stream>>>(h, whb, bias, v_w, s_part);
        softmax_kernel<<<BATCH, 512, 0, stream>>>(s_part, mask, a_buf);
        r_f32_part_kernel<<<BATCH * 32, 256, 0, stream>>>(h, a_buf, r_part);
        r_reduce_kernel<<<BATCH, 256, 0, stream>>>(r_part, out);
    }
}

// Round 5
// 548.236 us; speedup vs baseline: 1.1732x; 1.0113x over previous
//
#include <hip/hip_runtime.h>
#include <hip/hip_bf16.h>

// ---------- types ----------
typedef short  bf16x8s __attribute__((ext_vector_type(8)));  // 8 bf16 (4 VGPRs)
typedef float  f32x4   __attribute__((ext_vector_type(4)));  // 4 fp32 acc

#define BATCH 32
#define SEQL  2048
#define NROWS (BATCH * SEQL)   // 65536
#define IN    1024
#define HID   1024

// workspace layout
#define WHB_OFF   0u          // 2 MB   bf16 W_h
#define BIAS_OFF  0x200000u   // 4 KB
#define SPART_OFF 0x210000u   // 4 MB   s partials, ROW-MAJOR [65536][16]
#define HB_OFF    0x650000u   // 128 MB bf16 h
#define WS_NEED_BF16 ((size_t)HB_OFF + (size_t)NROWS * IN * 2)

// pack two fp32 -> two bf16 (round-up-on-half via +0x8000, v_perm byte select)
__device__ __forceinline__ unsigned int pack2bf(float f0, float f1) {
    unsigned int u0 = __float_as_uint(f0) + 0x8000u;
    unsigned int u1 = __float_as_uint(f1) + 0x8000u;
    return __builtin_amdgcn_perm(u1, u0, 0x07060302u);
}

__device__ __forceinline__ float tanh_fast(float x) {
    float xc = fminf(fmaxf(x, -15.f), 15.f);
    float t  = __builtin_amdgcn_exp2f(xc * 2.8853900817779268f); // e^(2x)
    return (t - 1.f) * __builtin_amdgcn_rcpf(t + 1.f);
}

// async 16B global->LDS (DMA; LDS dest = wave-uniform base + lane*16)
__device__ __forceinline__ void gl2lds16(const void* g, void* l) {
    __builtin_amdgcn_global_load_lds(
        (const __attribute__((address_space(1))) unsigned int*)g,
        (__attribute__((address_space(3))) unsigned int*)l, 16, 0, 0);
}

// XCD-locality swizzle: the 8 cb-siblings of a row-block share bi%8 -> same XCD
// (round-robin) -> A row-block L2-resident across re-reads. [R2: FETCH 1.06GB->92MB]
__device__ __forceinline__ void block_map(int bi, int& rb, int& cb) {
    int xcd  = bi & 7;
    int slot = bi >> 3;
    rb = xcd + 8 * (slot >> 3);
    cb = slot & 7;
}

// ---------- kernel 1: fused [W_h->bf16 + bias] (blocks 0..1023) and h->bf16 (rest) ----
__global__ __launch_bounds__(256) void prep_kernel(const float* __restrict__ ln_w,
                                                   const float* __restrict__ ln_b,
                                                   const float* __restrict__ vq,
                                                   const float* __restrict__ h,
                                                   unsigned short* __restrict__ whb,
                                                   float* __restrict__ bias,
                                                   unsigned short* __restrict__ hb) {
    const int bi = blockIdx.x;
    const int t  = threadIdx.x;
    if (bi < 1024) {
        const int n = bi;
        const int wave = t >> 6;
        const int lane = t & 63;
        float4 v = ((const float4*)(ln_w + (size_t)n * 2048))[t];
        uint2 pk;
        pk.x = pack2bf(v.x, v.y);
        pk.y = pack2bf(v.z, v.w);
        *(uint2*)(whb + (size_t)n * 1024 + t * 4) = pk;
        const float* wrow = ln_w + (size_t)n * 2048 + 1024;
        float s = 0.f;
        #pragma unroll
        for (int j = 0; j < 4; ++j) {
            int k = t + j * 256;
            s += wrow[k] * vq[k];
        }
        #pragma unroll
        for (int off = 32; off; off >>= 1) s += __shfl_xor(s, off);
        __shared__ float red[4];
        if (lane == 0) red[wave] = s;
        __syncthreads();
        if (t == 0) bias[n] = ln_b[n] + red[0] + red[1] + red[2] + red[3];
    } else {
        size_t idx = ((size_t)(bi - 1024) * 256 + t) * 8;
        float4 a = *(const float4*)(h + idx);
        float4 b = *(const float4*)(h + idx + 4);
        uint4 p;
        p.x = pack2bf(a.x, a.y); p.y = pack2bf(a.z, a.w);
        p.z = pack2bf(b.x, b.y); p.w = pack2bf(b.z, b.w);
        *(uint4*)(hb + idx) = p;
    }
}

// ---------- kernel 2: bf16 GEMM, BM=256 x BN=128, BK=32, 8 waves (R0 structure) ------
// Single-buffer 24KB LDS, stage->barrier->compute per K-step. Occupancy (~4 blk/CU)
// provides the latency hiding; explicit dbuf regressed (R2: occ 43->23%, 172->246us).
// epilogue: s_part[row][16] (row-major) = partial of sum_cols tanh(pre+bias)*v_w
__global__ __launch_bounds__(512) void gemm256_kernel(const unsigned short* __restrict__ hb,
                                                      const unsigned short* __restrict__ whb,
                                                      const float* __restrict__ bias,
                                                      const float* __restrict__ vw,
                                                      float* __restrict__ s_part) {
    __shared__ __align__(16) unsigned short As[8192]; // 16 KB: 256 rows x 32 shorts
    __shared__ __align__(16) unsigned short Bs[4096]; // 8 KB : 128 rows x 32 shorts

    const int tid = threadIdx.x;
    int rb, cb;
    block_map(blockIdx.x, rb, cb);
    const int wave = tid >> 6;
    const int lane = tid & 63;
    const int quad = lane >> 4;
    const int l15  = lane & 15;
    const int wy   = wave >> 1;          // 0..3 row band
    const int wx   = wave & 1;           // 0..1 col band
    const int row0 = rb * 256;
    const int col0 = cb * 128;

    // DMA staging (proven layout: row stride 32 shorts; slot sg holds k-group
    // sg^swz(row), swz=(row>>1)&3; LDS dest lane-linear tid*16B).
    // 512 threads: A issue0 rows 0..127, issue1 rows 128..255; B one issue rows 0..127.
    const int srow = tid >> 2;           // 0..127
    const int sg   = tid & 3;
    const int swz  = (srow >> 1) & 3;
    const unsigned short* gA0 = hb  + (size_t)(row0 + srow) * 1024 + ((sg ^ swz) * 8);
    const unsigned short* gA1 = gA0 + (size_t)128 * 1024;
    const unsigned short* gB0 = whb + (size_t)(col0 + srow) * 1024 + ((sg ^ swz) * 8);
    unsigned short* lA0 = As + tid * 8;          // bytes [0, 8192)
    unsigned short* lA1 = As + 4096 + tid * 8;   // bytes [8192, 16384)
    unsigned short* lB0 = Bs + tid * 8;          // bytes [0, 8192)

    // fragment read pointers (k-invariant; slot = quad ^ ((row>>1)&3))
    const unsigned short* rA[4];
    const unsigned short* rB[4];
    #pragma unroll
    for (int i = 0; i < 4; ++i) {
        int ra = wy * 64 + i * 16 + l15;         // 0..255
        rA[i] = As + ra * 32 + ((quad ^ ((ra >> 1) & 3)) * 8);
        int rn = wx * 64 + i * 16 + l15;         // 0..127
        rB[i] = Bs + rn * 32 + ((quad ^ ((rn >> 1) & 3)) * 8);
    }

    f32x4 acc[4][4];
    #pragma unroll
    for (int i = 0; i < 4; ++i)
        #pragma unroll
        for (int j = 0; j < 4; ++j)
            acc[i][j] = (f32x4){0.f, 0.f, 0.f, 0.f};

    for (int k0 = 0; k0 < 1024; k0 += 32) {
        __syncthreads();                 // prev iter's frag reads complete
        gl2lds16(gA0 + k0, lA0);
        gl2lds16(gA1 + k0, lA1);
        gl2lds16(gB0 + k0, lB0);
        __syncthreads();                 // DMA drained (barrier waits vmcnt(0))

        bf16x8s af[4], bfv[4];
        #pragma unroll
        for (int i = 0; i < 4; ++i) af[i]  = *(const bf16x8s*)rA[i];
        #pragma unroll
        for (int i = 0; i < 4; ++i) bfv[i] = *(const bf16x8s*)rB[i];
        #pragma unroll
        for (int mt = 0; mt < 4; ++mt)
            #pragma unroll
            for (int nt = 0; nt < 4; ++nt)
                acc[mt][nt] = __builtin_amdgcn_mfma_f32_16x16x32_bf16(af[mt], bfv[nt], acc[mt][nt], 0, 0, 0);
    }

    // epilogue: C/D layout col=lane&15, row=quad*4+r [m89/m91]
    const int colb = col0 + wx * 64 + l15;
    float vwv[4], bv[4];
    #pragma unroll
    for (int nt = 0; nt < 4; ++nt) {
        vwv[nt] = vw[colb + nt * 16];
        bv[nt]  = bias[colb + nt * 16];
    }
    const int rowb = row0 + wy * 64 + quad * 4;
    const int colp = cb * 2 + wx;        // partial slot 0..15
    #pragma unroll
    for (int mt = 0; mt < 4; ++mt) {
        #pragma unroll
        for (int r = 0; r < 4; ++r) {
            float p = 0.f;
            #pragma unroll
            for (int nt = 0; nt < 4; ++nt)
                p += tanh_fast(acc[mt][nt][r] + bv[nt]) * vwv[nt];
            p += __shfl_xor(p, 1);
            p += __shfl_xor(p, 2);
            p += __shfl_xor(p, 4);
            p += __shfl_xor(p, 8);
            if (l15 == 0) s_part[(size_t)(rowb + mt * 16 + r) * 16 + colp] = p;
        }
    }
}

// ---------- kernel 2b: fp32-A fallback (inline pack), only if ws too small ----------
__global__ __launch_bounds__(256) void gemm_f32_kernel(const float* __restrict__ hmat,
                                                       const unsigned short* __restrict__ whb,
                                                       const float* __restrict__ bias,
                                                       const float* __restrict__ vw,
                                                       float* __restrict__ s_part) {
    __shared__ __align__(16) unsigned short As[4096];
    __shared__ __align__(16) unsigned short Bs[4096];
    const int tid = threadIdx.x;
    int rb, cb;
    block_map(blockIdx.x, rb, cb);
    const int wave = tid >> 6;
    const int lane = tid & 63;
    const int quad = lane >> 4;
    const int l15  = lane & 15;
    const int wy   = wave >> 1;
    const int wx   = wave & 1;
    const int row0 = rb * 128;
    const int col0 = cb * 128;
    const int srow = tid >> 2;
    const int sg   = tid & 3;
    const int swz  = (srow >> 1) & 3;
    const float*          gA0 = hmat + (size_t)(row0 + srow)      * 1024 + sg * 8;
    const float*          gA1 = hmat + (size_t)(row0 + srow + 64) * 1024 + sg * 8;
    const unsigned short* gB0 = whb  + (size_t)(col0 + srow)      * 1024 + ((sg ^ swz) * 8);
    unsigned short* wA0 = As + srow * 32 + ((sg ^ swz) * 8);
    unsigned short* wA1 = wA0 + 64 * 32;
    unsigned short* lB0 = Bs + tid * 8;
    const unsigned short* rA[4];
    const unsigned short* rB[4];
    #pragma unroll
    for (int i = 0; i < 4; ++i) {
        int ra = wy * 64 + i * 16 + l15;
        rA[i] = As + ra * 32 + ((quad ^ ((ra >> 1) & 3)) * 8);
        int rn = wx * 64 + i * 16 + l15;
        rB[i] = Bs + rn * 32 + ((quad ^ ((rn >> 1) & 3)) * 8);
    }
    f32x4 acc[4][4];
    #pragma unroll
    for (int i = 0; i < 4; ++i)
        #pragma unroll
        for (int j = 0; j < 4; ++j)
            acc[i][j] = (f32x4){0.f, 0.f, 0.f, 0.f};
    for (int k0 = 0; k0 < 1024; k0 += 32) {
        float4 va0 = *(const float4*)(gA0 + k0);
        float4 va1 = *(const float4*)(gA0 + k0 + 4);
        float4 va2 = *(const float4*)(gA1 + k0);
        float4 va3 = *(const float4*)(gA1 + k0 + 4);
        __syncthreads();
        gl2lds16(gB0 + k0, lB0);
        gl2lds16(gB0 + 65536 + k0, lB0 + 2048);
        uint4 pa0, pa1;
        pa0.x = pack2bf(va0.x, va0.y); pa0.y = pack2bf(va0.z, va0.w);
        pa0.z = pack2bf(va1.x, va1.y); pa0.w = pack2bf(va1.z, va1.w);
        pa1.x = pack2bf(va2.x, va2.y); pa1.y = pack2bf(va2.z, va2.w);
        pa1.z = pack2bf(va3.x, va3.y); pa1.w = pack2bf(va3.z, va3.w);
        *(uint4*)wA0 = pa0;
        *(uint4*)wA1 = pa1;
        __syncthreads();
        bf16x8s af[4], bfv[4];
        #pragma unroll
        for (int i = 0; i < 4; ++i) af[i]  = *(const bf16x8s*)rA[i];
        #pragma unroll
        for (int i = 0; i < 4; ++i) bfv[i] = *(const bf16x8s*)rB[i];
        #pragma unroll
        for (int mt = 0; mt < 4; ++mt)
            #pragma unroll
            for (int nt = 0; nt < 4; ++nt)
                acc[mt][nt] = __builtin_amdgcn_mfma_f32_16x16x32_bf16(af[mt], bfv[nt], acc[mt][nt], 0, 0, 0);
    }
    const int colb = col0 + wx * 64 + l15;
    float vwv[4], bv[4];
    #pragma unroll
    for (int nt = 0; nt < 4; ++nt) {
        vwv[nt] = vw[colb + nt * 16];
        bv[nt]  = bias[colb + nt * 16];
    }
    const int rowb = row0 + wy * 64 + quad * 4;
    const int colp = cb * 2 + wx;
    #pragma unroll
    for (int mt = 0; mt < 4; ++mt) {
        #pragma unroll
        for (int r = 0; r < 4; ++r) {
            float p = 0.f;
            #pragma unroll
            for (int nt = 0; nt < 4; ++nt)
                p += tanh_fast(acc[mt][nt][r] + bv[nt]) * vwv[nt];
            p += __shfl_xor(p, 1);
            p += __shfl_xor(p, 2);
            p += __shfl_xor(p, 4);
            p += __shfl_xor(p, 8);
            if (l15 == 0) s_part[(size_t)(rowb + mt * 16 + r) * 16 + colp] = p;
        }
    }
}

// ---------- kernel 3: FUSED softmax + r (one dispatch replaces 3) ----------
// grid = 256 blocks: wg = cc*32 + b  (b=0..31 batch, cc=0..7 column-chunk of 128).
// wg%8 = b%8 -> all 8 cc-siblings of a batch share an XCD -> s_part[b] L2-resident.
// Phase 1: block redundantly computes softmax a[0..2047] for batch b into LDS
//          (reads s_part[b] 128KB coalesced + mask; 2K exp - trivial VALU).
// Phase 2: wave w accumulates rows l=w+8i (i=0..255); lane owns 2 cols (uint load,
//          256B/row/wave contiguous); cross-wave LDS reduce; direct out write.
// No a_buf, no r_part, no reduce dispatch, no out zeroing, no atomics.
__global__ __launch_bounds__(512) void fused_sm_r_bf16(const float* __restrict__ s_part,
                                                       const int* __restrict__ mask,
                                                       const unsigned short* __restrict__ hb,
                                                       float* __restrict__ out) {
    const int wg   = blockIdx.x;
    const int b    = wg & 31;
    const int cc   = wg >> 5;
    const int t    = threadIdx.x;
    const int w    = t >> 6;
    const int lane = t & 63;

    __shared__ float a_lds[2048];
    __shared__ float red[8][128];
    __shared__ float redm[8];
    __shared__ float reds[8];

    // ---- phase 1: softmax for batch b ----
    float sv[4];
    float mx = -3.0e38f;
    #pragma unroll
    for (int j = 0; j < 4; ++j) {
        int l = t + j * 512;
        const float4* pr = (const float4*)(s_part + ((size_t)b * 2048 + l) * 16);
        float4 q0 = pr[0], q1 = pr[1], q2 = pr[2], q3 = pr[3];
        float v = (q0.x + q0.y + q0.z + q0.w) + (q1.x + q1.y + q1.z + q1.w)
                + (q2.x + q2.y + q2.z + q2.w) + (q3.x + q3.y + q3.z + q3.w);
        if (mask[b * 2048 + l] == 0) v -= 10000.f;
        sv[j] = v;
        mx = fmaxf(mx, v);
    }
    #pragma unroll
    for (int off = 32; off; off >>= 1) mx = fmaxf(mx, __shfl_xor(mx, off));
    if (lane == 0) redm[w] = mx;
    __syncthreads();
    mx = redm[0];
    #pragma unroll
    for (int i = 1; i < 8; ++i) mx = fmaxf(mx, redm[i]);
    float sum = 0.f;
    #pragma unroll
    for (int j = 0; j < 4; ++j) {
        float e = __expf(sv[j] - mx);
        a_lds[t + j * 512] = e;
        sum += e;
    }
    #pragma unroll
    for (int off = 32; off; off >>= 1) sum += __shfl_xor(sum, off);
    if (lane == 0) reds[w] = sum;
    __syncthreads();
    sum = reds[0];
    #pragma unroll
    for (int i = 1; i < 8; ++i) sum += reds[i];
    const float inv = 1.f / sum;
    #pragma unroll
    for (int j = 0; j < 4; ++j)
        a_lds[t + j * 512] *= inv;       // each thread scales the 4 it wrote
    __syncthreads();

    // ---- phase 2: r accumulation, 128 cols owned by this block ----
    // lane owns cols c0, c0+1 (uint = 2 bf16); wave reads 256B/row contiguous.
    const unsigned int* hp = (const unsigned int*)
        (hb + (size_t)b * 2048 * 1024 + cc * 128 + lane * 2);
    float acc0 = 0.f, acc1 = 0.f;
    #pragma unroll 8
    for (int i = 0; i < 256; ++i) {
        const int l = w + i * 8;
        unsigned int v = hp[(size_t)l * 512];  // row stride 1024 shorts = 512 uints
        float av = a_lds[l];                   // LDS broadcast (uniform per wave)
        acc0 += av * __uint_as_float(v << 16);
        acc1 += av * __uint_as_float(v & 0xffff0000u);
    }
    red[w][lane * 2]     = acc0;
    red[w][lane * 2 + 1] = acc1;
    __syncthreads();
    if (t < 128) {
        float s = 0.f;
        #pragma unroll
        for (int i = 0; i < 8; ++i) s += red[i][t];
        out[b * 1024 + cc * 128 + t] = s;
    }
}

// ---------- kernel 3b: fused fallback reading f32 h ----------
__global__ __launch_bounds__(512) void fused_sm_r_f32(const float* __restrict__ s_part,
                                                      const int* __restrict__ mask,
                                                      const float* __restrict__ hmat,
                                                      float* __restrict__ out) {
    const int wg   = blockIdx.x;
    const int b    = wg & 31;
    const int cc   = wg >> 5;
    const int t    = threadIdx.x;
    const int w    = t >> 6;
    const int lane = t & 63;

    __shared__ float a_lds[2048];
    __shared__ float red[8][128];
    __shared__ float redm[8];
    __shared__ float reds[8];

    float sv[4];
    float mx = -3.0e38f;
    #pragma unroll
    for (int j = 0; j < 4; ++j) {
        int l = t + j * 512;
        const float4* pr = (const float4*)(s_part + ((size_t)b * 2048 + l) * 16);
        float4 q0 = pr[0], q1 = pr[1], q2 = pr[2], q3 = pr[3];
        float v = (q0.x + q0.y + q0.z + q0.w) + (q1.x + q1.y + q1.z + q1.w)
                + (q2.x + q2.y + q2.z + q2.w) + (q3.x + q3.y + q3.z + q3.w);
        if (mask[b * 2048 + l] == 0) v -= 10000.f;
        sv[j] = v;
        mx = fmaxf(mx, v);
    }
    #pragma unroll
    for (int off = 32; off; off >>= 1) mx = fmaxf(mx, __shfl_xor(mx, off));
    if (lane == 0) redm[w] = mx;
    __syncthreads();
    mx = redm[0];
    #pragma unroll
    for (int i = 1; i < 8; ++i) mx = fmaxf(mx, redm[i]);
    float sum = 0.f;
    #pragma unroll
    for (int j = 0; j < 4; ++j) {
        float e = __expf(sv[j] - mx);
        a_lds[t + j * 512] = e;
        sum += e;
    }
    #pragma unroll
    for (int off = 32; off; off >>= 1) sum += __shfl_xor(sum, off);
    if (lane == 0) reds[w] = sum;
    __syncthreads();
    sum = reds[0];
    #pragma unroll
    for (int i = 1; i < 8; ++i) sum += reds[i];
    const float inv = 1.f / sum;
    #pragma unroll
    for (int j = 0; j < 4; ++j)
        a_lds[t + j * 512] *= inv;
    __syncthreads();

    const float2* hp = (const float2*)
        (hmat + (size_t)b * 2048 * 1024 + cc * 128 + lane * 2);
    float acc0 = 0.f, acc1 = 0.f;
    #pragma unroll 8
    for (int i = 0; i < 256; ++i) {
        const int l = w + i * 8;
        float2 v = hp[(size_t)l * 512];        // row stride 1024 floats = 512 float2
        float av = a_lds[l];
        acc0 += av * v.x;
        acc1 += av * v.y;
    }
    red[w][lane * 2]     = acc0;
    red[w][lane * 2 + 1] = acc1;
    __syncthreads();
    if (t < 128) {
        float s = 0.f;
        #pragma unroll
        for (int i = 0; i < 8; ++i) s += red[i][t];
        out[b * 1024 + cc * 128 + t] = s;
    }
}

// ---------- launch (3 dispatches) ----------
extern "C" void kernel_launch(void* const* d_in, const int* in_sizes, int n_in,
                              void* d_out, int out_size, void* d_ws, size_t ws_size,
                              hipStream_t stream) {
    const float* h    = (const float*)d_in[0];
    const int*   mask = (const int*)d_in[1];
    const float* ln_w = (const float*)d_in[2];
    const float* ln_b = (const float*)d_in[3];
    const float* v_w  = (const float*)d_in[4];
    const float* vq   = (const float*)d_in[5];
    float* out = (float*)d_out;

    char* ws = (char*)d_ws;
    unsigned short* whb = (unsigned short*)(ws + WHB_OFF);
    float* bias         = (float*)(ws + BIAS_OFF);
    float* s_part       = (float*)(ws + SPART_OFF);
    unsigned short* hb  = (unsigned short*)(ws + HB_OFF);

    const bool use_bf16_h = (ws_size >= WS_NEED_BF16);

    if (use_bf16_h) {
        prep_kernel<<<1024 + 32768, 256, 0, stream>>>(ln_w, ln_b, vq, h, whb, bias, hb);
        gemm256_kernel<<<(NROWS / 256) * (HID / 128), 512, 0, stream>>>(hb, whb, bias, v_w, s_part);
        fused_sm_r_bf16<<<256, 512, 0, stream>>>(s_part, mask, hb, out);
    } else {
        prep_kernel<<<1024, 256, 0, stream>>>(ln_w, ln_b, vq, h, whb, bias, hb);
        gemm_f32_kernel<<<(NROWS / 128) * (HID / 128), 256, 0, stream>>>(h, whb, bias, v_w, s_part);
        fused_sm_r_f32<<<256, 512, 0, stream>>>(s_part, mask, h, out);
    }
}